// Round 1
// baseline (97.780 us; speedup 1.0000x reference)
//
#include <hip/hip_runtime.h>
#include <cstdint>

#define IMG_ELEMS 784      // 28*28
#define SLOT_ELEMS 832     // padded: conv of garbage lanes reads up to idx 815
#define NP 676             // 26*26 conv outputs
#define NOUT 10
#define ITS 11             // ceil(676/64)
#define WAVES_PER_BLOCK 4
#define BLOCKS 768         // 3 blocks/CU * 256 CUs

typedef const __attribute__((address_space(1))) void* gp1_t;
typedef __attribute__((address_space(3))) void* lp3_t;

__global__ __launch_bounds__(256, 3) void fused_digit_kernel(
    const float* __restrict__ x,
    const float* __restrict__ cw9,
    const float* __restrict__ Wlin,
    const float* __restrict__ bias,
    float* __restrict__ out,
    int nimg, int nwaves)
{
    __shared__ float smem[WAVES_PER_BLOCK * SLOT_ELEMS];
    const int tid  = threadIdx.x;
    const int lane = tid & 63;
    const int widb = tid >> 6;
    const int gwave = blockIdx.x * WAVES_PER_BLOCK + widb;
    float* slot = &smem[widb * SLOT_ELEMS];

    // zero the pad region once (floats 784..831); wave-private, no barrier needed
    if (lane < (SLOT_ELEMS - IMG_ELEMS)) slot[IMG_ELEMS + lane] = 0.0f;

    // uniform conv weights + bias (expect s_load)
    float cw[9];
#pragma unroll
    for (int k = 0; k < 9; ++k) cw[k] = cw9[k];
    float bv[NOUT];
#pragma unroll
    for (int o = 0; o < NOUT; ++o) bv[o] = bias[o];

    // per-lane W fragment (image-independent) + per-lane LDS base offsets
    float wt[ITS][NOUT];
    int boff[ITS];
#pragma unroll
    for (int it = 0; it < ITS; ++it) {
        int p = lane + it * 64;
        int i = p / 26;
        int j = p - i * 26;
        boff[it] = i * 28 + j;
        const bool v = (p < NP);
#pragma unroll
        for (int o = 0; o < NOUT; ++o)
            wt[it][o] = v ? Wlin[p * NOUT + o] : 0.0f;
    }

    for (int img = gwave; img < nimg; img += nwaves) {
        const float* src = x + (size_t)img * IMG_ELEMS;

        // stage image into this wave's LDS slot: 3x width-16 + 1x width-4 tail
#pragma unroll
        for (int k = 0; k < 3; ++k) {
            __builtin_amdgcn_global_load_lds(
                (gp1_t)(src + k * 256 + lane * 4),
                (lp3_t)(slot + k * 256),
                16, 0, 0);
        }
        if (lane < 16) {
            __builtin_amdgcn_global_load_lds(
                (gp1_t)(src + 768 + lane),
                (lp3_t)(slot + 768),
                4, 0, 0);
        }
        asm volatile("s_waitcnt vmcnt(0)" ::: "memory");

        float acc[NOUT];
#pragma unroll
        for (int o = 0; o < NOUT; ++o) acc[o] = 0.0f;

#pragma unroll
        for (int it = 0; it < ITS; ++it) {
            const float* r = slot + boff[it];
            float s = r[0] * cw[0];
            s = fmaf(r[1],  cw[1], s);
            s = fmaf(r[2],  cw[2], s);
            s = fmaf(r[28], cw[3], s);
            s = fmaf(r[29], cw[4], s);
            s = fmaf(r[30], cw[5], s);
            s = fmaf(r[56], cw[6], s);
            s = fmaf(r[57], cw[7], s);
            s = fmaf(r[58], cw[8], s);
            s = fmaxf(s, 0.0f);
#pragma unroll
            for (int o = 0; o < NOUT; ++o)
                acc[o] = fmaf(s, wt[it][o], acc[o]);
        }

        // 64-lane butterfly reduce of the 10 partial outputs
#pragma unroll
        for (int st = 0; st < 6; ++st) {
            const int m = 1 << st;
#pragma unroll
            for (int o = 0; o < NOUT; ++o)
                acc[o] += __shfl_xor(acc[o], m, 64);
        }

        if (lane == 0) {
            float* po = out + (size_t)img * NOUT;
#pragma unroll
            for (int k = 0; k < 5; ++k) {
                float2 v2 = make_float2(acc[2 * k] + bv[2 * k],
                                        acc[2 * k + 1] + bv[2 * k + 1]);
                *reinterpret_cast<float2*>(po + 2 * k) = v2;
            }
        }
    }
}

extern "C" void kernel_launch(void* const* d_in, const int* in_sizes, int n_in,
                              void* d_out, int out_size, void* d_ws, size_t ws_size,
                              hipStream_t stream) {
    const float* x   = (const float*)d_in[0];
    const float* cw  = (const float*)d_in[1];
    const float* W   = (const float*)d_in[2];
    const float* b   = (const float*)d_in[3];
    float* out = (float*)d_out;

    const int nimg   = in_sizes[0] / IMG_ELEMS;
    const int blocks = BLOCKS;
    const int nwaves = blocks * WAVES_PER_BLOCK;

    hipLaunchKernelGGL(fused_digit_kernel, dim3(blocks), dim3(256), 0, stream,
                       x, cw, W, b, out, nimg, nwaves);
}

// Round 3
// 86.732 us; speedup vs baseline: 1.1274x; 1.1274x over previous
//
#include <hip/hip_runtime.h>
#include <cstdint>

#define IMG_ELEMS 784
#define IMG_STRIDE_DW 395          // 790 bf16 per image slot; odd dword stride for banks
#define SLOT_DWORDS (16 * IMG_STRIDE_DW)   // 6320 dwords = 25,280 B per wave
#define WAVES_PER_BLOCK 2
#define BLOCKS 768                 // 3 blocks/CU * 256 CU

typedef __attribute__((ext_vector_type(8))) short short8;
typedef __attribute__((ext_vector_type(4))) float f32x4;

union ABu { uint32_t u[4]; short8 v; };

__device__ inline uint32_t pk_bf16(float a, float b) {
    uint32_t r;
    asm("v_cvt_pk_bf16_f32 %0, %1, %2" : "=v"(r) : "v"(a), "v"(b));
    return r;  // lo = bf16(a), hi = bf16(b)
}
__device__ inline float bflo(uint32_t u) { return __uint_as_float(u << 16); }
__device__ inline float bfhi(uint32_t u) { return __uint_as_float(u & 0xffff0000u); }

__global__ __launch_bounds__(128, 2) void fused_digit_mfma_kernel(
    const float* __restrict__ x,
    const float* __restrict__ cw9,
    const float* __restrict__ Wlin,
    const float* __restrict__ bias,
    float* __restrict__ out,
    int ngroups, int nwaves)
{
    __shared__ uint32_t smem[WAVES_PER_BLOCK * SLOT_DWORDS];
    const int tid  = threadIdx.x;
    const int lane = tid & 63;
    uint32_t* slot = &smem[(tid >> 6) * SLOT_DWORDS];
    const int wave_id = blockIdx.x * WAVES_PER_BLOCK + (tid >> 6);

    const int rc = lane & 15;   // A-row (image in group) AND B-col (output idx)
    const int g  = lane >> 4;   // k-subgroup: features 8g..8g+7 of each 32-wide chunk

    // uniform conv weights
    float cw[9];
#pragma unroll
    for (int k = 0; k < 9; ++k) cw[k] = cw9[k];

    const float bv = (rc < 10) ? bias[rc < 10 ? rc : 0] : 0.0f;

    // ---- B fragments: W in bf16, one frag per conv row (K-chunk), kept in VGPRs ----
    ABu bf[26];
#pragma unroll
    for (int c = 0; c < 26; ++c) {
#pragma unroll
        for (int m = 0; m < 4; ++m) {
            const int c0 = 8 * g + 2 * m;
            const int c1 = c0 + 1;
            const bool v0 = (c0 < 26) && (rc < 10);
            const bool v1 = (c1 < 26) && (rc < 10);
            const int i0 = v0 ? ((c * 26 + c0) * 10 + rc) : 0;
            const int i1 = v1 ? ((c * 26 + c1) * 10 + rc) : 0;
            const float w0 = v0 ? Wlin[i0] : 0.0f;
            const float w1 = v1 ? Wlin[i1] : 0.0f;
            bf[c].u[m] = pk_bf16(w0, w1);
        }
    }

    // zero inter-image gap elements (784..789 of each slot → dwords 392..394):
    // conv reads of padded cols touch these; must be finite (NaN x 0 = NaN in MFMA)
    if (lane < 48) slot[IMG_STRIDE_DW * (lane / 3) + 392 + (lane % 3)] = 0;
    asm volatile("s_waitcnt lgkmcnt(0)" ::: "memory");

    for (int grp = wave_id; grp < ngroups; grp += nwaves) {
        // ---- stage 16 images: f32 global -> bf16 LDS (coalesced dwordx4) ----
        const float4* src = (const float4*)(x) + (size_t)grp * (16 * 196);
#pragma unroll
        for (int im = 0; im < 16; ++im) {
            const float4* s4 = src + im * 196;
            uint32_t* dst = slot + IMG_STRIDE_DW * im;
#pragma unroll
            for (int k = 0; k < 3; ++k) {
                float4 val = s4[k * 64 + lane];
                dst[2 * (k * 64 + lane)]     = pk_bf16(val.x, val.y);
                dst[2 * (k * 64 + lane) + 1] = pk_bf16(val.z, val.w);
            }
            if (lane < 4) {
                float4 val = s4[192 + lane];
                dst[2 * (192 + lane)]     = pk_bf16(val.x, val.y);
                dst[2 * (192 + lane) + 1] = pk_bf16(val.z, val.w);
            }
        }
        asm volatile("s_waitcnt lgkmcnt(0)" ::: "memory");

        // ---- conv row r -> A fragment -> MFMA accumulate ----
        f32x4 acc = {0.f, 0.f, 0.f, 0.f};
        const uint32_t* ib = slot + IMG_STRIDE_DW * rc + 4 * g;
#pragma unroll
        for (int r = 0; r < 26; ++r) {
            float vv[3][10];
#pragma unroll
            for (int dr = 0; dr < 3; ++dr) {
                const uint32_t* p = ib + 14 * (r + dr);
                const uint32_t u0 = p[0], u1 = p[1], u2 = p[2], u3 = p[3], u4 = p[4];
                vv[dr][0] = bflo(u0); vv[dr][1] = bfhi(u0);
                vv[dr][2] = bflo(u1); vv[dr][3] = bfhi(u1);
                vv[dr][4] = bflo(u2); vv[dr][5] = bfhi(u2);
                vv[dr][6] = bflo(u3); vv[dr][7] = bfhi(u3);
                vv[dr][8] = bflo(u4); vv[dr][9] = bfhi(u4);
            }
            ABu a;
#pragma unroll
            for (int m = 0; m < 4; ++m) {
                float o[2];
#pragma unroll
                for (int h = 0; h < 2; ++h) {
                    const int j = 2 * m + h;
                    float s = vv[0][j] * cw[0];
                    s = fmaf(vv[0][j + 1], cw[1], s);
                    s = fmaf(vv[0][j + 2], cw[2], s);
                    s = fmaf(vv[1][j],     cw[3], s);
                    s = fmaf(vv[1][j + 1], cw[4], s);
                    s = fmaf(vv[1][j + 2], cw[5], s);
                    s = fmaf(vv[2][j],     cw[6], s);
                    s = fmaf(vv[2][j + 1], cw[7], s);
                    s = fmaf(vv[2][j + 2], cw[8], s);
                    o[h] = fmaxf(s, 0.f);
                }
                a.u[m] = pk_bf16(o[0], o[1]);
            }
            acc = __builtin_amdgcn_mfma_f32_16x16x32_bf16(a.v, bf[r].v, acc, 0, 0, 0);
        }

        // ---- store: D[row=img][col=out], row=(lane>>4)*4+q, col=lane&15 ----
        if (rc < 10) {
            float* po = out + ((size_t)grp * 16 + (size_t)g * 4) * 10 + rc;
#pragma unroll
            for (int q = 0; q < 4; ++q) po[q * 10] = acc[q] + bv;
        }
    }
}

extern "C" void kernel_launch(void* const* d_in, const int* in_sizes, int n_in,
                              void* d_out, int out_size, void* d_ws, size_t ws_size,
                              hipStream_t stream) {
    const float* x   = (const float*)d_in[0];
    const float* cw  = (const float*)d_in[1];
    const float* W   = (const float*)d_in[2];
    const float* b   = (const float*)d_in[3];
    float* out = (float*)d_out;

    const int nimg    = in_sizes[0] / IMG_ELEMS;
    const int ngroups = nimg / 16;
    const int nwaves  = BLOCKS * WAVES_PER_BLOCK;

    hipLaunchKernelGGL(fused_digit_mfma_kernel, dim3(BLOCKS), dim3(128), 0, stream,
                       x, cw, W, b, out, ngroups, nwaves);
}

// Round 4
// 53.162 us; speedup vs baseline: 1.8393x; 1.6315x over previous
//
#include <hip/hip_runtime.h>
#include <cstdint>

#define IMG_ELEMS 784
#define IMG_DW 392                 // 784 bf16 = 392 dwords of real data
#define IMG_STRIDE_DW 395          // +3 pad dwords (conv overreach), odd stride
#define NIMG_GRP 16
#define SLOT_DWORDS (NIMG_GRP * IMG_STRIDE_DW)   // 6320 dwords = 25,280 B
#define SCRATCH_DW 1024            // 4 waves x 64 lanes x 4 f32 partial acc
#define BLOCKS 1280                // 5 blocks/CU x 256 CU

typedef __attribute__((ext_vector_type(8))) short short8;
typedef __attribute__((ext_vector_type(4))) float f32x4;

union ABu { uint32_t u[4]; short8 v; };

__device__ inline uint32_t pk_bf16(float a, float b) {
    uint32_t r;
    asm("v_cvt_pk_bf16_f32 %0, %1, %2" : "=v"(r) : "v"(a), "v"(b));
    return r;  // lo = bf16(a), hi = bf16(b)
}
__device__ inline float bflo(uint32_t u) { return __uint_as_float(u << 16); }
__device__ inline float bfhi(uint32_t u) { return __uint_as_float(u & 0xffff0000u); }

__global__ __launch_bounds__(256, 4) void fused_digit_mfma_kernel(
    const float* __restrict__ x,
    const float* __restrict__ cw9,
    const float* __restrict__ Wlin,
    const float* __restrict__ bias,
    float* __restrict__ out,
    int ngroups)
{
    __shared__ uint32_t smem[SLOT_DWORDS + SCRATCH_DW];
    const int tid  = threadIdx.x;
    const int lane = tid & 63;
    const int widb = tid >> 6;
    const int rc = lane & 15;   // A-row (image in group) AND B-col (output idx)
    const int g  = lane >> 4;   // k-subgroup: features 8g..8g+7 of each 32-chunk

    // uniform conv weights
    float cw[9];
#pragma unroll
    for (int k = 0; k < 9; ++k) cw[k] = cw9[k];
    const float bv = (rc < 10) ? bias[rc] : 0.0f;

    // K-split across the 4 waves: conv rows [rstart, rstart+rcnt)
    const int rstart = (widb < 2) ? widb * 7 : 14 + (widb - 2) * 6;
    const int rcnt   = (widb < 2) ? 7 : 6;

    // B fragments for this wave's conv rows only (bf16 W in VGPRs)
    ABu bf[7];
#pragma unroll
    for (int rr = 0; rr < 7; ++rr) {
        const int r = rstart + rr;
#pragma unroll
        for (int m = 0; m < 4; ++m) {
            const int c0 = 8 * g + 2 * m;
            const int c1 = c0 + 1;
            const bool v0 = (rr < rcnt) && (c0 < 26) && (rc < 10);
            const bool v1 = (rr < rcnt) && (c1 < 26) && (rc < 10);
            const float w0 = v0 ? Wlin[(r * 26 + c0) * 10 + rc] : 0.0f;
            const float w1 = v1 ? Wlin[(r * 26 + c1) * 10 + rc] : 0.0f;
            bf[rr].u[m] = pk_bf16(w0, w1);
        }
    }

    // zero the 3 pad dwords of each image slot once (conv overreach must be
    // finite: NaN x 0 = NaN inside MFMA). Staging never touches dwords 392..394.
    if (tid < 48) smem[IMG_STRIDE_DW * (tid / 3) + IMG_DW + (tid % 3)] = 0;

    for (int grp = blockIdx.x; grp < ngroups; grp += gridDim.x) {
        // ---- cooperative stage: wave widb converts its 4 images f32->bf16 ----
        const float4* src = (const float4*)x + (size_t)grp * (NIMG_GRP * 196);
#pragma unroll
        for (int k = 0; k < 4; ++k) {
            const int im = widb * 4 + k;
            const float4* s4 = src + im * 196;
            uint32_t* dst = smem + IMG_STRIDE_DW * im;
#pragma unroll
            for (int j = 0; j < 3; ++j) {
                float4 val = s4[j * 64 + lane];
                dst[2 * (j * 64 + lane)]     = pk_bf16(val.x, val.y);
                dst[2 * (j * 64 + lane) + 1] = pk_bf16(val.z, val.w);
            }
        }
        if (lane < 16) {  // tails of the 4 images: float4 idx 192..195
            const int im = widb * 4 + (lane >> 2);
            const int j  = 192 + (lane & 3);
            float4 val = src[im * 196 + j];
            uint32_t* dst = smem + IMG_STRIDE_DW * im;
            dst[2 * j]     = pk_bf16(val.x, val.y);
            dst[2 * j + 1] = pk_bf16(val.z, val.w);
        }
        __syncthreads();

        // ---- this wave's share of conv rows -> A frags -> MFMA partial acc ----
        f32x4 acc = {0.f, 0.f, 0.f, 0.f};
        const uint32_t* ib = smem + IMG_STRIDE_DW * rc + 4 * g;
#pragma unroll
        for (int rr = 0; rr < 7; ++rr) {
            if (rr < rcnt) {
                const int r = rstart + rr;
                float vv[3][10];
#pragma unroll
                for (int dr = 0; dr < 3; ++dr) {
                    const uint32_t* p = ib + 14 * (r + dr);
                    const uint32_t u0 = p[0], u1 = p[1], u2 = p[2], u3 = p[3], u4 = p[4];
                    vv[dr][0] = bflo(u0); vv[dr][1] = bfhi(u0);
                    vv[dr][2] = bflo(u1); vv[dr][3] = bfhi(u1);
                    vv[dr][4] = bflo(u2); vv[dr][5] = bfhi(u2);
                    vv[dr][6] = bflo(u3); vv[dr][7] = bfhi(u3);
                    vv[dr][8] = bflo(u4); vv[dr][9] = bfhi(u4);
                }
                ABu a;
#pragma unroll
                for (int m = 0; m < 4; ++m) {
                    float o[2];
#pragma unroll
                    for (int h = 0; h < 2; ++h) {
                        const int j = 2 * m + h;
                        float s = vv[0][j] * cw[0];
                        s = fmaf(vv[0][j + 1], cw[1], s);
                        s = fmaf(vv[0][j + 2], cw[2], s);
                        s = fmaf(vv[1][j],     cw[3], s);
                        s = fmaf(vv[1][j + 1], cw[4], s);
                        s = fmaf(vv[1][j + 2], cw[5], s);
                        s = fmaf(vv[2][j],     cw[6], s);
                        s = fmaf(vv[2][j + 1], cw[7], s);
                        s = fmaf(vv[2][j + 2], cw[8], s);
                        o[h] = fmaxf(s, 0.f);
                    }
                    a.u[m] = pk_bf16(o[0], o[1]);
                }
                acc = __builtin_amdgcn_mfma_f32_16x16x32_bf16(a.v, bf[rr].v, acc, 0, 0, 0);
            }
        }

        // ---- cross-wave K-reduction via LDS scratch ----
        float* sc = (float*)(smem + SLOT_DWORDS);
        *reinterpret_cast<f32x4*>(sc + widb * 256 + lane * 4) = acc;
        __syncthreads();

        if (widb == 0) {
            const float* scr = sc + lane * 4;
            f32x4 s0 = *reinterpret_cast<const f32x4*>(scr);
            f32x4 s1 = *reinterpret_cast<const f32x4*>(scr + 256);
            f32x4 s2 = *reinterpret_cast<const f32x4*>(scr + 512);
            f32x4 s3 = *reinterpret_cast<const f32x4*>(scr + 768);
            if (rc < 10) {
                float* po = out + ((size_t)grp * NIMG_GRP + (size_t)g * 4) * 10 + rc;
#pragma unroll
                for (int q = 0; q < 4; ++q)
                    po[q * 10] = s0[q] + s1[q] + s2[q] + s3[q] + bv;
            }
        }
    }
}

extern "C" void kernel_launch(void* const* d_in, const int* in_sizes, int n_in,
                              void* d_out, int out_size, void* d_ws, size_t ws_size,
                              hipStream_t stream) {
    const float* x   = (const float*)d_in[0];
    const float* cw  = (const float*)d_in[1];
    const float* W   = (const float*)d_in[2];
    const float* b   = (const float*)d_in[3];
    float* out = (float*)d_out;

    const int nimg    = in_sizes[0] / IMG_ELEMS;
    const int ngroups = nimg / NIMG_GRP;

    hipLaunchKernelGGL(fused_digit_mfma_kernel, dim3(BLOCKS), dim3(256), 0, stream,
                       x, cw, W, b, out, ngroups);
}